// Round 1
// baseline (9592.139 us; speedup 1.0000x reference)
//
#include <hip/hip_runtime.h>
#include <math.h>

// Soft k-means (Clusterator): N=100000, D=512, K=256, temp=30, 11 iterations.
// d_out = [mu (256*512) | r (N*256)]. r region doubles as the per-iteration
// r buffer so no large workspace is needed (~2 MB ws total).

#define DIMD 512
#define KCL 256
#define NSPLIT 64

// -------- row norms of data: inv_norm[i] = 1/(||data_i||+1e-6) --------
__global__ void row_norms_k(const float* __restrict__ x,
                            float* __restrict__ inv_norm, int n) {
  int wave = threadIdx.x >> 6;
  int lane = threadIdx.x & 63;
  int row = blockIdx.x * 4 + wave;
  if (row >= n) return;
  const float4* xr = (const float4*)(x + (size_t)row * DIMD);
  float4 a = xr[lane];
  float4 b = xr[lane + 64];
  float s = a.x*a.x + a.y*a.y + a.z*a.z + a.w*a.w
          + b.x*b.x + b.y*b.y + b.z*b.z + b.w*b.w;
#pragma unroll
  for (int m = 32; m >= 1; m >>= 1) s += __shfl_xor(s, m);
  if (lane == 0) inv_norm[row] = 1.0f / (sqrtf(s) + 1e-6f);
}

// -------- mu_n = normalize(mu_src [/ colsum]); zero accumulators --------
__global__ void mu_norm_k(const float* __restrict__ mu_src,
                          const float* __restrict__ colsum_in,
                          float* __restrict__ mu_n,
                          float* __restrict__ mu_acc_z,
                          float* __restrict__ colsum_z,
                          int use_colsum) {
  int k = blockIdx.x;
  int t = threadIdx.x;
  float inv_c = 1.0f;
  if (use_colsum) inv_c = 1.0f / colsum_in[k];
  float v0 = mu_src[k * DIMD + t] * inv_c;
  float v1 = mu_src[k * DIMD + t + 256] * inv_c;
  float s = v0 * v0 + v1 * v1;
#pragma unroll
  for (int m = 32; m >= 1; m >>= 1) s += __shfl_xor(s, m);
  __shared__ float sred[4];
  int lane = t & 63, wv = t >> 6;
  if (lane == 0) sred[wv] = s;
  __syncthreads();
  s = sred[0] + sred[1] + sred[2] + sred[3];
  float inv = 1.0f / (sqrtf(s) + 1e-6f);
  mu_n[k * DIMD + t] = v0 * inv;
  mu_n[k * DIMD + t + 256] = v1 * inv;
  mu_acc_z[k * DIMD + t] = 0.0f;
  mu_acc_z[k * DIMD + t + 256] = 0.0f;
  if (t == 0) colsum_z[k] = 0.0f;
}

// -------- out_mu = mu_acc / colsum --------
__global__ void final_mu_k(const float* __restrict__ mu_acc,
                           const float* __restrict__ colsum,
                           float* __restrict__ out) {
  int k = blockIdx.x;
  int t = threadIdx.x;
  float ic = 1.0f / colsum[k];
  out[k * DIMD + t] = mu_acc[k * DIMD + t] * ic;
  out[k * DIMD + t + 256] = mu_acc[k * DIMD + t + 256] * ic;
}

// -------- dist = data_n @ mu_n^T ; r = softmax(temp*dist) ; colsum += --------
// Block tile: 64 rows x 256 cols. 256 threads; thread = (ty=t>>4, tx=t&15).
// Thread owns rows ty*4+{0..3}, cols {j*64 + tx*4 + c : j,c in 0..3}.
__global__ __launch_bounds__(256) void dist_softmax_k(
    const float* __restrict__ data, const float* __restrict__ inv_norm,
    const float* __restrict__ mu_n, float* __restrict__ r_out,
    float* __restrict__ colsum, const float* __restrict__ temp_p, int n) {
  __shared__ float a_lds[64][36];   // [row][dd], stride 36 (144B, 16B-aligned)
  __shared__ float b_lds[32][260];  // [dd][k],   stride 260 (16B-aligned)
  __shared__ float s_cs[256];

  int t = threadIdx.x;
  int tx = t & 15, ty = t >> 4;
  int i0 = blockIdx.x * 64;

  float acc[4][16];
#pragma unroll
  for (int rr = 0; rr < 4; ++rr)
#pragma unroll
    for (int x = 0; x < 16; ++x) acc[rr][x] = 0.0f;

  for (int ch = 0; ch < 16; ++ch) {
    int d0 = ch * 32;
    // stage A tile (64 rows x 32 d), normalized
#pragma unroll
    for (int q = 0; q < 2; ++q) {
      int lin = t + 256 * q;
      int row = lin >> 3, f4 = lin & 7;
      int gi = i0 + row;
      if (gi > n - 1) gi = n - 1;
      float4 v = *(const float4*)(data + (size_t)gi * DIMD + d0 + f4 * 4);
      float sc = inv_norm[gi];
      v.x *= sc; v.y *= sc; v.z *= sc; v.w *= sc;
      *(float4*)&a_lds[row][f4 * 4] = v;
    }
    // stage B tile transposed (32 dd x 256 k)
#pragma unroll
    for (int q = 0; q < 8; ++q) {
      int lin = t + 256 * q;
      int k = lin >> 3, f4 = lin & 7;
      float4 v = *(const float4*)(mu_n + k * DIMD + d0 + f4 * 4);
      b_lds[f4 * 4 + 0][k] = v.x;
      b_lds[f4 * 4 + 1][k] = v.y;
      b_lds[f4 * 4 + 2][k] = v.z;
      b_lds[f4 * 4 + 3][k] = v.w;
    }
    __syncthreads();
#pragma unroll
    for (int dd = 0; dd < 32; ++dd) {
      float a_[4];
#pragma unroll
      for (int rr = 0; rr < 4; ++rr) a_[rr] = a_lds[ty * 4 + rr][dd];
      float b_[16];
#pragma unroll
      for (int j = 0; j < 4; ++j) {
        float4 bv = *(const float4*)&b_lds[dd][j * 64 + tx * 4];
        b_[j * 4 + 0] = bv.x; b_[j * 4 + 1] = bv.y;
        b_[j * 4 + 2] = bv.z; b_[j * 4 + 3] = bv.w;
      }
#pragma unroll
      for (int rr = 0; rr < 4; ++rr)
#pragma unroll
        for (int x = 0; x < 16; ++x) acc[rr][x] += a_[rr] * b_[x];
    }
    __syncthreads();
  }

  // softmax over K per row (row spans the 16 tx-lanes of one ty group)
  float tempv = temp_p[0];
#pragma unroll
  for (int rr = 0; rr < 4; ++rr) {
    float mx = -3.4e38f;
#pragma unroll
    for (int x = 0; x < 16; ++x) {
      acc[rr][x] *= tempv;
      mx = fmaxf(mx, acc[rr][x]);
    }
#pragma unroll
    for (int m = 1; m <= 8; m <<= 1) mx = fmaxf(mx, __shfl_xor(mx, m));
    float s = 0.0f;
#pragma unroll
    for (int x = 0; x < 16; ++x) {
      float e = __expf(acc[rr][x] - mx);
      acc[rr][x] = e;
      s += e;
    }
#pragma unroll
    for (int m = 1; m <= 8; m <<= 1) s += __shfl_xor(s, m);
    float is = 1.0f / s;
#pragma unroll
    for (int x = 0; x < 16; ++x) acc[rr][x] *= is;
  }

  // store r and accumulate column sums
  float cs[16];
#pragma unroll
  for (int x = 0; x < 16; ++x) cs[x] = 0.0f;
#pragma unroll
  for (int rr = 0; rr < 4; ++rr) {
    int gi = i0 + ty * 4 + rr;
    if (gi < n) {
#pragma unroll
      for (int j = 0; j < 4; ++j) {
        float4 v;
        v.x = acc[rr][j * 4 + 0]; v.y = acc[rr][j * 4 + 1];
        v.z = acc[rr][j * 4 + 2]; v.w = acc[rr][j * 4 + 3];
        *(float4*)(r_out + (size_t)gi * KCL + j * 64 + tx * 4) = v;
      }
#pragma unroll
      for (int x = 0; x < 16; ++x) cs[x] += acc[rr][x];
    }
  }
  // reduce cs over the 4 ty groups in each wave (lane bits 4,5)
#pragma unroll
  for (int x = 0; x < 16; ++x) {
    cs[x] += __shfl_xor(cs[x], 16);
    cs[x] += __shfl_xor(cs[x], 32);
  }
  s_cs[t] = 0.0f;
  __syncthreads();
  if ((t & 48) == 0) {  // one lane per (wave, tx)
#pragma unroll
    for (int x = 0; x < 16; ++x) {
      int col = (x >> 2) * 64 + tx * 4 + (x & 3);
      atomicAdd(&s_cs[col], cs[x]);
    }
  }
  __syncthreads();
  atomicAdd(&colsum[t], s_cs[t]);
}

// -------- mu_acc += r^T @ data_n (K x D, inner N, split over NSPLIT) --------
// Block tile: 128 k x 128 d; thread owns k = k0+ty*8+{0..7},
// d = d0 + {j*64 + tx*4 + c : j in 0..1, c in 0..3}.
__global__ __launch_bounds__(256) void update_k(
    const float* __restrict__ r_glob, const float* __restrict__ data,
    const float* __restrict__ inv_norm, float* __restrict__ mu_acc, int n) {
  __shared__ float r_lds[32][132];
  __shared__ float x_lds[32][132];
  int t = threadIdx.x, tx = t & 15, ty = t >> 4;
  int bx = blockIdx.x;
  int k0 = (bx & 1) * 128;
  int d0 = (bx >> 1) * 128;
  int ns = blockIdx.y;
  int chunk = (n + NSPLIT - 1) / NSPLIT;
  int ibeg = ns * chunk;
  int iend = ibeg + chunk;
  if (iend > n) iend = n;

  float acc[8][8];
#pragma unroll
  for (int rr = 0; rr < 8; ++rr)
#pragma unroll
    for (int cc = 0; cc < 8; ++cc) acc[rr][cc] = 0.0f;

  for (int i0 = ibeg; i0 < iend; i0 += 32) {
#pragma unroll
    for (int q = 0; q < 4; ++q) {
      int lin = t + 256 * q;
      int ii = lin >> 5, f4 = lin & 31;
      int gi = i0 + ii;
      float4 rv = make_float4(0.f, 0.f, 0.f, 0.f);
      float4 xv = make_float4(0.f, 0.f, 0.f, 0.f);
      if (gi < iend) {
        rv = *(const float4*)(r_glob + (size_t)gi * KCL + k0 + f4 * 4);
        xv = *(const float4*)(data + (size_t)gi * DIMD + d0 + f4 * 4);
        float sc = inv_norm[gi];
        xv.x *= sc; xv.y *= sc; xv.z *= sc; xv.w *= sc;
      }
      *(float4*)&r_lds[ii][f4 * 4] = rv;
      *(float4*)&x_lds[ii][f4 * 4] = xv;
    }
    __syncthreads();
#pragma unroll 4
    for (int ii = 0; ii < 32; ++ii) {
      float4 ra = *(const float4*)&r_lds[ii][ty * 8];
      float4 rb = *(const float4*)&r_lds[ii][ty * 8 + 4];
      float4 xa = *(const float4*)&x_lds[ii][tx * 4];
      float4 xb = *(const float4*)&x_lds[ii][64 + tx * 4];
      float rv[8] = {ra.x, ra.y, ra.z, ra.w, rb.x, rb.y, rb.z, rb.w};
      float xv[8] = {xa.x, xa.y, xa.z, xa.w, xb.x, xb.y, xb.z, xb.w};
#pragma unroll
      for (int rr = 0; rr < 8; ++rr)
#pragma unroll
        for (int cc = 0; cc < 8; ++cc) acc[rr][cc] += rv[rr] * xv[cc];
    }
    __syncthreads();
  }
#pragma unroll
  for (int rr = 0; rr < 8; ++rr)
#pragma unroll
    for (int cc = 0; cc < 8; ++cc) {
      int k = k0 + ty * 8 + rr;
      int d = d0 + (cc >> 2) * 64 + tx * 4 + (cc & 3);
      atomicAdd(&mu_acc[k * DIMD + d], acc[rr][cc]);
    }
}

extern "C" void kernel_launch(void* const* d_in, const int* in_sizes, int n_in,
                              void* d_out, int out_size, void* d_ws,
                              size_t ws_size, hipStream_t stream) {
  const float* embeds = (const float*)d_in[0];
  const float* temp_p = (const float*)d_in[1];
  const float* init = (const float*)d_in[2];
  int n = in_sizes[0] / DIMD;  // 100000

  float* out_mu = (float*)d_out;             // [256*512]
  float* out_r = (float*)d_out + KCL * DIMD; // [n*256] — also the per-iter r buffer

  float* ws = (float*)d_ws;
  float* inv_norm = ws;                          // n floats
  float* mu_n = ws + ((n + 3) & ~3);             // 256*512
  float* mu_acc = mu_n + KCL * DIMD;             // 256*512
  float* colsum = mu_acc + KCL * DIMD;           // 256

  row_norms_k<<<(n + 3) / 4, 256, 0, stream>>>(embeds, inv_norm, n);
  // mu_n = normalize(init); zero mu_acc/colsum
  mu_norm_k<<<KCL, 256, 0, stream>>>(init, colsum, mu_n, mu_acc, colsum, 0);

  for (int it = 0; it <= 10; ++it) {
    dist_softmax_k<<<(n + 63) / 64, 256, 0, stream>>>(
        embeds, inv_norm, mu_n, out_r, colsum, temp_p, n);
    update_k<<<dim3(8, NSPLIT), 256, 0, stream>>>(out_r, embeds, inv_norm,
                                                  mu_acc, n);
    if (it < 10) {
      // mu_n = normalize(mu_acc/colsum); re-zero mu_acc/colsum
      mu_norm_k<<<KCL, 256, 0, stream>>>(mu_acc, colsum, mu_n, mu_acc, colsum,
                                         1);
    } else {
      final_mu_k<<<KCL, 256, 0, stream>>>(mu_acc, colsum, out_mu);
    }
  }
}

// Round 2
// 3878.385 us; speedup vs baseline: 2.4732x; 2.4732x over previous
//
#include <hip/hip_runtime.h>
#include <math.h>

// Soft k-means via bf16 hi/lo 3-product MFMA emulation of fp32.
// N=100000, D=512, K=256, temp=30, 11 iterations.
// d_out = [mu (256*512) | r (N*256)]. Iters 0-9 store r as packed
// (bf16hi<<16)|bf16lo uint32 in the r region; iter 10 stores fp32 r.

#define DIMD 512
#define KCL 256
#define NSPLIT 96

typedef __attribute__((ext_vector_type(8))) short short8;
typedef __attribute__((ext_vector_type(4))) short short4v;
typedef __attribute__((ext_vector_type(4))) float float4v;

__device__ __forceinline__ short f2bf(float x) {
  union { float f; unsigned u; } v; v.f = x;
  unsigned r = v.u + 0x7fff + ((v.u >> 16) & 1);   // round-to-nearest-even
  return (short)(r >> 16);
}
__device__ __forceinline__ float bf2f(short b) {
  union { unsigned u; float f; } v;
  v.u = ((unsigned)(unsigned short)b) << 16;
  return v.f;
}

// -------- row norms of data: inv_norm[i] = 1/(||data_i||+1e-6) --------
__global__ void row_norms_k(const float* __restrict__ x,
                            float* __restrict__ inv_norm, int n) {
  int wave = threadIdx.x >> 6;
  int lane = threadIdx.x & 63;
  int row = blockIdx.x * 4 + wave;
  if (row >= n) return;
  const float4* xr = (const float4*)(x + (size_t)row * DIMD);
  float4 a = xr[lane];
  float4 b = xr[lane + 64];
  float s = a.x*a.x + a.y*a.y + a.z*a.z + a.w*a.w
          + b.x*b.x + b.y*b.y + b.z*b.z + b.w*b.w;
#pragma unroll
  for (int m = 32; m >= 1; m >>= 1) s += __shfl_xor(s, m);
  if (lane == 0) inv_norm[row] = 1.0f / (sqrtf(s) + 1e-6f);
}

// -------- mu_n = normalize(mu_src [/ colsum]) -> bf16 hi/lo; zero accums ----
__global__ void mu_norm_k(const float* __restrict__ mu_src,
                          const float* __restrict__ colsum_in,
                          short* __restrict__ mu_hi, short* __restrict__ mu_lo,
                          float* __restrict__ mu_acc_z,
                          float* __restrict__ colsum_z, int use_colsum) {
  int k = blockIdx.x;
  int t = threadIdx.x;
  float inv_c = 1.0f;
  if (use_colsum) inv_c = 1.0f / colsum_in[k];
  float v0 = mu_src[k * DIMD + t] * inv_c;
  float v1 = mu_src[k * DIMD + t + 256] * inv_c;
  float s = v0 * v0 + v1 * v1;
#pragma unroll
  for (int m = 32; m >= 1; m >>= 1) s += __shfl_xor(s, m);
  __shared__ float sred[4];
  int lane = t & 63, wv = t >> 6;
  if (lane == 0) sred[wv] = s;
  __syncthreads();
  s = sred[0] + sred[1] + sred[2] + sred[3];
  float inv = 1.0f / (sqrtf(s) + 1e-6f);
  float w0 = v0 * inv, w1 = v1 * inv;
  short h0 = f2bf(w0), h1 = f2bf(w1);
  mu_hi[k * DIMD + t] = h0;
  mu_hi[k * DIMD + t + 256] = h1;
  mu_lo[k * DIMD + t] = f2bf(w0 - bf2f(h0));
  mu_lo[k * DIMD + t + 256] = f2bf(w1 - bf2f(h1));
  mu_acc_z[k * DIMD + t] = 0.0f;
  mu_acc_z[k * DIMD + t + 256] = 0.0f;
  if (t == 0) colsum_z[k] = 0.0f;
}

// -------- out_mu = mu_acc / colsum --------
__global__ void final_mu_k(const float* __restrict__ mu_acc,
                           const float* __restrict__ colsum,
                           float* __restrict__ out) {
  int k = blockIdx.x;
  int t = threadIdx.x;
  float ic = 1.0f / colsum[k];
  out[k * DIMD + t] = mu_acc[k * DIMD + t] * ic;
  out[k * DIMD + t + 256] = mu_acc[k * DIMD + t + 256] * ic;
}

// -------- dist = data_n @ mu_n^T ; r = softmax(temp*dist) ; colsum += -------
// Block: 64 i-rows x 256 k-cols, 256 threads = 4 waves; wave wc owns cols
// wc*64..+63 as 4x4 tiles of 16x16x32 MFMA, bf16 hi/lo 3-product.
__global__ __launch_bounds__(256) void dist_mfma_k(
    const float* __restrict__ data, const float* __restrict__ inv_norm,
    const short* __restrict__ mu_hi, const short* __restrict__ mu_lo,
    unsigned* __restrict__ r_pack, float* __restrict__ r_f32, int write_f32,
    float* __restrict__ colsum, const float* __restrict__ temp_p, int n) {
  // rows: [i][d 0..31 = hi, 32..63 = lo], stride 72 (144 B) to break banks
  __shared__ __align__(16) short a_lds[64][72];
  __shared__ __align__(16) short b_lds[256][72];
  __shared__ __align__(16) float red[64][4];

  int t = threadIdx.x;
  int wave = t >> 6, lane = t & 63, q = lane >> 4, lx = lane & 15;
  int i0 = blockIdx.x * 64;

  float4v acc[4][4];
#pragma unroll
  for (int mt = 0; mt < 4; ++mt)
#pragma unroll
    for (int nt = 0; nt < 4; ++nt) acc[mt][nt] = (float4v)0.0f;

  for (int ch = 0; ch < 16; ++ch) {
    int d0 = ch * 32;
    // ---- stage A (64 x 32 fp32 -> hi/lo bf16) ----
    {
      int row = t >> 2, seg = t & 3;
      int gi = i0 + row;
      if (gi > n - 1) gi = n - 1;
      const float* p = data + (size_t)gi * DIMD + d0 + seg * 8;
      float4 x0 = *(const float4*)p;
      float4 x1 = *(const float4*)(p + 4);
      float sc = inv_norm[gi];
      float vv[8] = {x0.x * sc, x0.y * sc, x0.z * sc, x0.w * sc,
                     x1.x * sc, x1.y * sc, x1.z * sc, x1.w * sc};
      short8 hv, lv;
#pragma unroll
      for (int j = 0; j < 8; ++j) {
        short h = f2bf(vv[j]);
        hv[j] = h;
        lv[j] = f2bf(vv[j] - bf2f(h));
      }
      *(short8*)&a_lds[row][seg * 8] = hv;
      *(short8*)&a_lds[row][32 + seg * 8] = lv;
    }
    // ---- stage B (256 x 32, already bf16 hi/lo in ws) ----
    {
      int seg = t & 3, kb = t >> 2;
#pragma unroll
      for (int rep = 0; rep < 4; ++rep) {
        int k = rep * 64 + kb;
        short8 h = *(const short8*)(mu_hi + (size_t)k * DIMD + d0 + seg * 8);
        short8 l = *(const short8*)(mu_lo + (size_t)k * DIMD + d0 + seg * 8);
        *(short8*)&b_lds[k][seg * 8] = h;
        *(short8*)&b_lds[k][32 + seg * 8] = l;
      }
    }
    __syncthreads();
    short8 ah[4], al[4], bh[4], bl[4];
#pragma unroll
    for (int mt = 0; mt < 4; ++mt) {
      ah[mt] = *(const short8*)&a_lds[mt * 16 + lx][q * 8];
      al[mt] = *(const short8*)&a_lds[mt * 16 + lx][32 + q * 8];
    }
#pragma unroll
    for (int nt = 0; nt < 4; ++nt) {
      int kr = wave * 64 + nt * 16 + lx;
      bh[nt] = *(const short8*)&b_lds[kr][q * 8];
      bl[nt] = *(const short8*)&b_lds[kr][32 + q * 8];
    }
#pragma unroll
    for (int mt = 0; mt < 4; ++mt)
#pragma unroll
      for (int nt = 0; nt < 4; ++nt) {
        acc[mt][nt] = __builtin_amdgcn_mfma_f32_16x16x32_bf16(
            ah[mt], bh[nt], acc[mt][nt], 0, 0, 0);
        acc[mt][nt] = __builtin_amdgcn_mfma_f32_16x16x32_bf16(
            ah[mt], bl[nt], acc[mt][nt], 0, 0, 0);
        acc[mt][nt] = __builtin_amdgcn_mfma_f32_16x16x32_bf16(
            al[mt], bh[nt], acc[mt][nt], 0, 0, 0);
      }
    __syncthreads();
  }

  // ---- softmax over K=256 per row; |30*dist| <= ~30.5 so no max-shift ----
  float tempv = temp_p[0];
  float rs[4][4];
#pragma unroll
  for (int mt = 0; mt < 4; ++mt)
#pragma unroll
    for (int reg = 0; reg < 4; ++reg) {
      float s = 0.0f;
#pragma unroll
      for (int nt = 0; nt < 4; ++nt) {
        float e = __expf(tempv * acc[mt][nt][reg]);
        acc[mt][nt][reg] = e;
        s += e;
      }
      s += __shfl_xor(s, 1);
      s += __shfl_xor(s, 2);
      s += __shfl_xor(s, 4);
      s += __shfl_xor(s, 8);
      rs[mt][reg] = s;
    }
  if (lx == 0) {
#pragma unroll
    for (int mt = 0; mt < 4; ++mt)
#pragma unroll
      for (int reg = 0; reg < 4; ++reg)
        red[mt * 16 + q * 4 + reg][wave] = rs[mt][reg];
  }
  __syncthreads();

  float cs[4] = {0.0f, 0.0f, 0.0f, 0.0f};
#pragma unroll
  for (int mt = 0; mt < 4; ++mt)
#pragma unroll
    for (int reg = 0; reg < 4; ++reg) {
      int row = mt * 16 + q * 4 + reg;
      float4 v = *(const float4*)&red[row][0];
      float is = 1.0f / (v.x + v.y + v.z + v.w);
      int gi = i0 + row;
      bool ok = gi < n;
#pragma unroll
      for (int nt = 0; nt < 4; ++nt) {
        float r = acc[mt][nt][reg] * is;
        acc[mt][nt][reg] = r;
        if (ok) cs[nt] += r;
      }
      if (ok) {
        if (write_f32) {
#pragma unroll
          for (int nt = 0; nt < 4; ++nt)
            r_f32[(size_t)gi * KCL + wave * 64 + nt * 16 + lx] =
                acc[mt][nt][reg];
        } else {
#pragma unroll
          for (int nt = 0; nt < 4; ++nt) {
            float r = acc[mt][nt][reg];
            short h = f2bf(r);
            short l = f2bf(r - bf2f(h));
            r_pack[(size_t)gi * KCL + wave * 64 + nt * 16 + lx] =
                ((unsigned)(unsigned short)h << 16) | (unsigned short)l;
          }
        }
      }
    }
#pragma unroll
  for (int nt = 0; nt < 4; ++nt) {
    cs[nt] += __shfl_xor(cs[nt], 16);
    cs[nt] += __shfl_xor(cs[nt], 32);
  }
  if (q == 0) {
#pragma unroll
    for (int nt = 0; nt < 4; ++nt)
      atomicAdd(&colsum[wave * 64 + nt * 16 + lx], cs[nt]);
  }
}

// -------- mu_acc += r^T @ data_n via MFMA (transpose-staged operands) -------
// Block: 128 k x 128 d, 256 threads = 4 waves (2x2 of 64x64 wave tiles).
// Inner i split over NSPLIT; fp32 atomics into mu_acc.
__global__ __launch_bounds__(256) void update_mfma_k(
    const unsigned* __restrict__ r_src, int r_is_f32,
    const float* __restrict__ data, const float* __restrict__ inv_norm,
    float* __restrict__ mu_acc, int n) {
  __shared__ __align__(16) short rT[128][72];  // [k][i 0..31 hi, 32..63 lo]
  __shared__ __align__(16) short xT[128][72];  // [d][i hi/lo]

  int t = threadIdx.x, wave = t >> 6, lane = t & 63, q = lane >> 4,
      lx = lane & 15;
  int bx = blockIdx.x;
  int k0 = (bx & 1) * 128, d0 = (bx >> 1) * 128;
  int ns = blockIdx.y;
  int chunk = (n + NSPLIT - 1) / NSPLIT;
  int ibeg = ns * chunk;
  int iend = ibeg + chunk;
  if (iend > n) iend = n;
  int wk = wave >> 1, wd = wave & 1;
  int iq = t >> 5, kq = t & 31;  // staging coords: 4 i x 4 col block

  float4v acc[4][4];
#pragma unroll
  for (int mt = 0; mt < 4; ++mt)
#pragma unroll
    for (int nt = 0; nt < 4; ++nt) acc[mt][nt] = (float4v)0.0f;

  for (int ib = ibeg; ib < iend; ib += 32) {
    // ---- stage r tile (32 i x 128 k) transposed ----
    {
      short h[4][4], l[4][4];
#pragma unroll
      for (int ii = 0; ii < 4; ++ii) {
        int gi = ib + iq * 4 + ii;
        uint4 u = make_uint4(0u, 0u, 0u, 0u);
        if (gi < iend)
          u = *(const uint4*)(r_src + (size_t)gi * KCL + k0 + kq * 4);
        unsigned uu[4] = {u.x, u.y, u.z, u.w};
        if (r_is_f32) {
#pragma unroll
          for (int kk = 0; kk < 4; ++kk) {
            union { unsigned u; float f; } c; c.u = uu[kk];
            short hh = f2bf(c.f);
            h[ii][kk] = hh;
            l[ii][kk] = f2bf(c.f - bf2f(hh));
          }
        } else {
#pragma unroll
          for (int kk = 0; kk < 4; ++kk) {
            h[ii][kk] = (short)(uu[kk] >> 16);
            l[ii][kk] = (short)(uu[kk] & 0xffffu);
          }
        }
      }
#pragma unroll
      for (int kk = 0; kk < 4; ++kk) {
        short4v vh = {h[0][kk], h[1][kk], h[2][kk], h[3][kk]};
        short4v vl = {l[0][kk], l[1][kk], l[2][kk], l[3][kk]};
        *(short4v*)&rT[kq * 4 + kk][iq * 4] = vh;
        *(short4v*)&rT[kq * 4 + kk][32 + iq * 4] = vl;
      }
    }
    // ---- stage x tile (32 i x 128 d) normalized, transposed ----
    {
      short h[4][4], l[4][4];
#pragma unroll
      for (int ii = 0; ii < 4; ++ii) {
        int gi = ib + iq * 4 + ii;
        float4 x = make_float4(0.f, 0.f, 0.f, 0.f);
        float sc = 0.0f;
        if (gi < iend) {
          x = *(const float4*)(data + (size_t)gi * DIMD + d0 + kq * 4);
          sc = inv_norm[gi];
        }
        float vv[4] = {x.x * sc, x.y * sc, x.z * sc, x.w * sc};
#pragma unroll
        for (int kk = 0; kk < 4; ++kk) {
          short hh = f2bf(vv[kk]);
          h[ii][kk] = hh;
          l[ii][kk] = f2bf(vv[kk] - bf2f(hh));
        }
      }
#pragma unroll
      for (int kk = 0; kk < 4; ++kk) {
        short4v vh = {h[0][kk], h[1][kk], h[2][kk], h[3][kk]};
        short4v vl = {l[0][kk], l[1][kk], l[2][kk], l[3][kk]};
        *(short4v*)&xT[kq * 4 + kk][iq * 4] = vh;
        *(short4v*)&xT[kq * 4 + kk][32 + iq * 4] = vl;
      }
    }
    __syncthreads();
    short8 ah[4], al[4], bh[4], bl[4];
#pragma unroll
    for (int mt = 0; mt < 4; ++mt) {
      int kr = wk * 64 + mt * 16 + lx;
      ah[mt] = *(const short8*)&rT[kr][q * 8];
      al[mt] = *(const short8*)&rT[kr][32 + q * 8];
    }
#pragma unroll
    for (int nt = 0; nt < 4; ++nt) {
      int dr = wd * 64 + nt * 16 + lx;
      bh[nt] = *(const short8*)&xT[dr][q * 8];
      bl[nt] = *(const short8*)&xT[dr][32 + q * 8];
    }
#pragma unroll
    for (int mt = 0; mt < 4; ++mt)
#pragma unroll
      for (int nt = 0; nt < 4; ++nt) {
        acc[mt][nt] = __builtin_amdgcn_mfma_f32_16x16x32_bf16(
            ah[mt], bh[nt], acc[mt][nt], 0, 0, 0);
        acc[mt][nt] = __builtin_amdgcn_mfma_f32_16x16x32_bf16(
            ah[mt], bl[nt], acc[mt][nt], 0, 0, 0);
        acc[mt][nt] = __builtin_amdgcn_mfma_f32_16x16x32_bf16(
            al[mt], bh[nt], acc[mt][nt], 0, 0, 0);
      }
    __syncthreads();
  }
#pragma unroll
  for (int mt = 0; mt < 4; ++mt)
#pragma unroll
    for (int nt = 0; nt < 4; ++nt)
#pragma unroll
      for (int reg = 0; reg < 4; ++reg) {
        int k = k0 + wk * 64 + mt * 16 + q * 4 + reg;
        int d = d0 + wd * 64 + nt * 16 + lx;
        atomicAdd(&mu_acc[(size_t)k * DIMD + d], acc[mt][nt][reg]);
      }
}

extern "C" void kernel_launch(void* const* d_in, const int* in_sizes, int n_in,
                              void* d_out, int out_size, void* d_ws,
                              size_t ws_size, hipStream_t stream) {
  const float* embeds = (const float*)d_in[0];
  const float* temp_p = (const float*)d_in[1];
  const float* init = (const float*)d_in[2];
  int n = in_sizes[0] / DIMD;  // 100000

  float* out_mu = (float*)d_out;              // [256*512]
  float* out_r = (float*)d_out + KCL * DIMD;  // [n*256] fp32 / packed scratch

  float* wsf = (float*)d_ws;
  float* inv_norm = wsf;                     // n
  float* mu_acc = wsf + ((n + 3) & ~3);      // 256*512 fp32
  float* colsum = mu_acc + KCL * DIMD;       // 256
  short* mu_hi = (short*)(colsum + 256);     // 256*512 bf16
  short* mu_lo = mu_hi + KCL * DIMD;         // 256*512 bf16

  row_norms_k<<<(n + 3) / 4, 256, 0, stream>>>(embeds, inv_norm, n);
  mu_norm_k<<<KCL, 256, 0, stream>>>(init, colsum, mu_hi, mu_lo, mu_acc,
                                     colsum, 0);

  for (int it = 0; it <= 10; ++it) {
    int wf32 = (it == 10) ? 1 : 0;
    dist_mfma_k<<<(n + 63) / 64, 256, 0, stream>>>(
        embeds, inv_norm, mu_hi, mu_lo, (unsigned*)out_r, out_r, wf32, colsum,
        temp_p, n);
    update_mfma_k<<<dim3(8, NSPLIT), 256, 0, stream>>>(
        (const unsigned*)out_r, wf32, embeds, inv_norm, mu_acc, n);
    if (it < 10) {
      mu_norm_k<<<KCL, 256, 0, stream>>>(mu_acc, colsum, mu_hi, mu_lo, mu_acc,
                                         colsum, 1);
    } else {
      final_mu_k<<<KCL, 256, 0, stream>>>(mu_acc, colsum, out_mu);
    }
  }
}